// Round 6
// baseline (1230.384 us; speedup 1.0000x reference)
//
#include <hip/hip_runtime.h>

#define NV 200000
#define NE 1600000
#define CD 128
#define NBUCK 3125            // NV/64 buckets of 64 rows
#define NBLK 49
#define CHUNK 32768           // NBLK*CHUNK = 1,605,632 >= NE

// ---- workspace layout (bytes) ----
#define Y_OFF     0UL           // y bf16-packed: NV*CD*2 = 51,200,000
#define WB_OFF    51200000UL    // W bf16: 32,768
#define CNT_OFF   51232768UL    // NBLK*NBUCK ints = 612,500
#define TOT_OFF   51845376UL    // NBUCK ints
#define START_OFF 51857920UL    // NBUCK+1 ints
#define SCAT_OFF  51870464UL    // NE int2 = 12,800,000  (end ~64.7 MB)

typedef short  short8 __attribute__((ext_vector_type(8)));
typedef float  f32x4  __attribute__((ext_vector_type(4)));

__device__ __forceinline__ short bf16of(float f) {
    __bf16 h = (__bf16)f;
    return __builtin_bit_cast(short, h);
}

// ---------------- Kernel 0: W fp32 -> bf16 ----------------
__global__ __launch_bounds__(256) void k_cvtW(const float* __restrict__ W,
                                              unsigned short* __restrict__ Wb) {
    int i = blockIdx.x * 256 + threadIdx.x;
    float4 wv = reinterpret_cast<const float4*>(W)[i];
    ushort4 o;
    o.x = (unsigned short)bf16of(wv.x);
    o.y = (unsigned short)bf16of(wv.y);
    o.z = (unsigned short)bf16of(wv.z);
    o.w = (unsigned short)bf16of(wv.w);
    reinterpret_cast<ushort4*>(Wb)[i] = o;
}

// ---------------- Kernel 1: y(bf16) = x @ W^T via MFMA (proven round 5) ----------------
#define GEMM_BLOCKS 512
#define GEMM_WAVES (GEMM_BLOCKS * 4)
#define NTILES (NV / 16)

__global__ __launch_bounds__(256, 2) void gemm_mfma(const float* __restrict__ x,
                                                    const unsigned short* __restrict__ Wb,
                                                    unsigned short* __restrict__ y) {
    __shared__ __align__(16) short Wlds[2048 * 8];

    const int t = threadIdx.x;
    const int lane = t & 63;
    const int w = t >> 6;
    const int g = lane >> 4;

    {
        const uint4* Wg = reinterpret_cast<const uint4*>(Wb);
        uint4* L = reinterpret_cast<uint4*>(Wlds);
#pragma unroll
        for (int i = 0; i < 8; ++i) {
            int c = t + i * 256;
            int l = c & 63;
            int ks = (c >> 6) & 3;
            int tl = c >> 8;
            int row = 16 * tl + (l & 15);
            L[c] = Wg[row * 16 + ks * 4 + (l >> 4)];
        }
    }
    __syncthreads();

    short8 A[8][4];
    {
        const short8* L8 = reinterpret_cast<const short8*>(Wlds);
#pragma unroll
        for (int t8 = 0; t8 < 8; ++t8)
#pragma unroll
            for (int ks = 0; ks < 4; ++ks)
                A[t8][ks] = L8[(t8 * 4 + ks) * 64 + lane];
    }

    const int wgid = blockIdx.x * 4 + w;
    char* yb = reinterpret_cast<char*>(y);

    for (int tile = wgid; tile < NTILES; tile += GEMM_WAVES) {
        const int v0 = tile * 16;
        const int row = v0 + (lane & 15);
        const float4* xr = reinterpret_cast<const float4*>(x + (size_t)row * CD);

        float4 xf[8];
#pragma unroll
        for (int ks = 0; ks < 4; ++ks) {
            xf[2 * ks]     = xr[8 * ks + 2 * g];
            xf[2 * ks + 1] = xr[8 * ks + 2 * g + 1];
        }

        f32x4 acc[8];
#pragma unroll
        for (int t8 = 0; t8 < 8; ++t8) acc[t8] = (f32x4){0.f, 0.f, 0.f, 0.f};

#pragma unroll
        for (int ks = 0; ks < 4; ++ks) {
            short8 B;
            const float* f = reinterpret_cast<const float*>(&xf[2 * ks]);
#pragma unroll
            for (int j = 0; j < 8; ++j) B[j] = bf16of(f[j]);
#pragma unroll
            for (int t8 = 0; t8 < 8; ++t8)
                acc[t8] = __builtin_amdgcn_mfma_f32_16x16x32_bf16(A[t8][ks], B, acc[t8], 0, 0, 0);
        }

        const size_t rb = (size_t)(v0 + (lane & 15)) * 256;
#pragma unroll
        for (int t8 = 0; t8 < 8; ++t8) {
            ushort4 o;
            o.x = (unsigned short)bf16of(acc[t8][0]);
            o.y = (unsigned short)bf16of(acc[t8][1]);
            o.z = (unsigned short)bf16of(acc[t8][2]);
            o.w = (unsigned short)bf16of(acc[t8][3]);
            *reinterpret_cast<ushort4*>(yb + rb + t8 * 32 + g * 8) = o;
        }
    }
}

// ---------------- pc: per-chunk bucket histogram ----------------
__global__ __launch_bounds__(1024) void pc(const int* __restrict__ rows,
                                           int* __restrict__ cnt) {
    __shared__ int hist[NBUCK];
    const int t = threadIdx.x;
    for (int i = t; i < NBUCK; i += 1024) hist[i] = 0;
    __syncthreads();
    const int e0 = blockIdx.x * CHUNK;
    const int e1 = min(NE, e0 + CHUNK);
    for (int e = e0 + t; e < e1; e += 1024)
        atomicAdd(&hist[rows[e] >> 6], 1);
    __syncthreads();
    for (int i = t; i < NBUCK; i += 1024)
        cnt[(size_t)blockIdx.x * NBUCK + i] = hist[i];
}

// ---------------- ps: cross-block exclusive prefix per bucket (in-place) ----------------
__global__ __launch_bounds__(256) void ps(int* __restrict__ cnt,
                                          int* __restrict__ tot) {
    int g = blockIdx.x * 256 + threadIdx.x;
    if (g >= NBUCK) return;
    int running = 0;
    for (int blk = 0; blk < NBLK; ++blk) {
        int idx = blk * NBUCK + g;
        int c = cnt[idx];
        cnt[idx] = running;       // rel[blk][bk]
        running += c;
    }
    tot[g] = running;
}

// ---------------- pt: scan bucket totals -> start[0..NBUCK] ----------------
__global__ __launch_bounds__(1024) void pt(const int* __restrict__ tot,
                                           int* __restrict__ start) {
    __shared__ int s[1024];
    const int t = threadIdx.x;
    if (t == 0) start[NBUCK] = NE;
    int carry = 0;
    for (int c = 0; c < 4; ++c) {
        int idx = c * 1024 + t;
        int v = (idx < NBUCK) ? tot[idx] : 0;
        s[t] = v;
        __syncthreads();
        for (int d = 1; d < 1024; d <<= 1) {
            int add = (t >= d) ? s[t - d] : 0;
            __syncthreads();
            s[t] += add;
            __syncthreads();
        }
        if (idx < NBUCK) start[idx] = carry + s[t] - v;
        carry += s[1023];
        __syncthreads();
    }
}

// ---------------- px: scatter edges into bucket order (block-owned runs) ----------------
__global__ __launch_bounds__(1024) void px(const int* __restrict__ rows,
                                           const int* __restrict__ cols,
                                           const float* __restrict__ vals,
                                           const int* __restrict__ cnt,
                                           const int* __restrict__ start,
                                           int2* __restrict__ scat) {
    __shared__ int cur[NBUCK];
    const int t = threadIdx.x;
    for (int i = t; i < NBUCK; i += 1024)
        cur[i] = start[i] + cnt[(size_t)blockIdx.x * NBUCK + i];
    __syncthreads();
    const int e0 = blockIdx.x * CHUNK;
    const int e1 = min(NE, e0 + CHUNK);
    for (int e = e0 + t; e < e1; e += 1024) {
        int r = rows[e];
        int pos = atomicAdd(&cur[r >> 6], 1);
        scat[pos] = make_int2(cols[e] | ((r & 63) << 18), __float_as_int(vals[e]));
    }
}

// ---------------- gather2: one block per 64-row bucket, LDS f32 accumulators ----------------
__global__ __launch_bounds__(256) void k_gather2(const int* __restrict__ start,
                                                 const int2* __restrict__ scat,
                                                 const unsigned* __restrict__ y,
                                                 const float* __restrict__ b,
                                                 float* __restrict__ out) {
    __shared__ float acc[64 * CD];   // 32 KB
    const int t = threadIdx.x;
    float4* acc4 = reinterpret_cast<float4*>(acc);
#pragma unroll
    for (int i = 0; i < 8; ++i) acc4[t + i * 256] = make_float4(0.f, 0.f, 0.f, 0.f);
    __syncthreads();

    const int wid = t >> 6, lane = t & 63;
    const int s0 = start[blockIdx.x], s1 = start[blockIdx.x + 1];

    int e = s0 + wid;
    for (; e + 4 < s1; e += 8) {     // two edges in flight per wave
        int2 pa = scat[e];
        int2 pb = scat[e + 4];
        unsigned ua = y[(size_t)(pa.x & 0x3ffff) * 64 + lane];
        unsigned ub = y[(size_t)(pb.x & 0x3ffff) * 64 + lane];
        float va = __int_as_float(pa.y), vb = __int_as_float(pb.y);
        float* ra = &acc[(pa.x >> 18) * CD + 2 * lane];
        float* rb = &acc[(pb.x >> 18) * CD + 2 * lane];
        atomicAdd(ra,     va * __uint_as_float(ua << 16));
        atomicAdd(ra + 1, va * __uint_as_float(ua & 0xffff0000u));
        atomicAdd(rb,     vb * __uint_as_float(ub << 16));
        atomicAdd(rb + 1, vb * __uint_as_float(ub & 0xffff0000u));
    }
    if (e < s1) {
        int2 pa = scat[e];
        unsigned ua = y[(size_t)(pa.x & 0x3ffff) * 64 + lane];
        float va = __int_as_float(pa.y);
        float* ra = &acc[(pa.x >> 18) * CD + 2 * lane];
        atomicAdd(ra,     va * __uint_as_float(ua << 16));
        atomicAdd(ra + 1, va * __uint_as_float(ua & 0xffff0000u));
    }
    __syncthreads();

    const float4 bb = reinterpret_cast<const float4*>(b)[t & 31];
    float4* o4 = reinterpret_cast<float4*>(out) + (size_t)blockIdx.x * 2048;
#pragma unroll
    for (int i = 0; i < 8; ++i) {
        int idx = t + i * 256;       // row = idx>>5, chan-quad = idx&31 == t&31
        float4 a = acc4[idx];
        a.x += bb.x; a.y += bb.y; a.z += bb.z; a.w += bb.w;
        o4[idx] = a;
    }
}

extern "C" void kernel_launch(void* const* d_in, const int* in_sizes, int n_in,
                              void* d_out, int out_size, void* d_ws, size_t ws_size,
                              hipStream_t stream) {
    const float* x    = (const float*)d_in[0];
    const int*   rows = (const int*)d_in[1];
    const int*   cols = (const int*)d_in[2];
    const float* vals = (const float*)d_in[3];
    const float* Wm   = (const float*)d_in[4];
    const float* b    = (const float*)d_in[5];
    float* out = (float*)d_out;

    char* ws = (char*)d_ws;
    unsigned short* y  = (unsigned short*)(ws + Y_OFF);
    unsigned short* Wb = (unsigned short*)(ws + WB_OFF);
    int* cnt           = (int*)(ws + CNT_OFF);
    int* tot           = (int*)(ws + TOT_OFF);
    int* start         = (int*)(ws + START_OFF);
    int2* scat         = (int2*)(ws + SCAT_OFF);

    k_cvtW<<<16, 256, 0, stream>>>(Wm, Wb);
    gemm_mfma<<<GEMM_BLOCKS, 256, 0, stream>>>(x, Wb, y);
    pc<<<NBLK, 1024, 0, stream>>>(rows, cnt);
    ps<<<(NBUCK + 255) / 256, 256, 0, stream>>>(cnt, tot);
    pt<<<1, 1024, 0, stream>>>(tot, start);
    px<<<NBLK, 1024, 0, stream>>>(rows, cols, vals, cnt, start, scat);
    k_gather2<<<NBUCK, 256, 0, stream>>>(start, scat, (const unsigned*)y, b, out);
}

// Round 7
// 246.325 us; speedup vs baseline: 4.9950x; 4.9950x over previous
//
#include <hip/hip_runtime.h>

#define NV 200000
#define NE 1600000
#define CD 128
#define NBUCK 3125            // NV/64 buckets of 64 rows
#define NBLK 49
#define CHUNK 32768           // NBLK*CHUNK = 1,605,632 >= NE

// ---- workspace layout (bytes) ----
#define Y_OFF      0UL           // y bf16-packed: NV*CD*2 = 51,200,000
#define WB_OFF     51200000UL    // W bf16: 32,768
#define CNT_OFF    51232768UL    // NBLK*NBUCK ints = 612,500
#define TOT_OFF    51845376UL    // NBUCK ints
#define START_OFF  51857920UL    // NBUCK+1 ints (padded)
#define SCAT_OFF   51870464UL    // NE int2 = 12,800,000
#define ROWOFF_OFF 64670464UL    // NV+1 ints (padded to 800,256)
#define SCAT2_OFF  65470720UL    // NE int2 = 12,800,000  (end ~78.3 MB)

typedef short  short8 __attribute__((ext_vector_type(8)));
typedef float  f32x4  __attribute__((ext_vector_type(4)));

__device__ __forceinline__ short bf16of(float f) {
    __bf16 h = (__bf16)f;
    return __builtin_bit_cast(short, h);
}

// ---------------- Kernel 0: W fp32 -> bf16 ----------------
__global__ __launch_bounds__(256) void k_cvtW(const float* __restrict__ W,
                                              unsigned short* __restrict__ Wb) {
    int i = blockIdx.x * 256 + threadIdx.x;
    float4 wv = reinterpret_cast<const float4*>(W)[i];
    ushort4 o;
    o.x = (unsigned short)bf16of(wv.x);
    o.y = (unsigned short)bf16of(wv.y);
    o.z = (unsigned short)bf16of(wv.z);
    o.w = (unsigned short)bf16of(wv.w);
    reinterpret_cast<ushort4*>(Wb)[i] = o;
}

// ---------------- Kernel 1: y(bf16) = x @ W^T via MFMA (proven round 5) ----------------
#define GEMM_BLOCKS 512
#define GEMM_WAVES (GEMM_BLOCKS * 4)
#define NTILES (NV / 16)

__global__ __launch_bounds__(256, 2) void gemm_mfma(const float* __restrict__ x,
                                                    const unsigned short* __restrict__ Wb,
                                                    unsigned short* __restrict__ y) {
    __shared__ __align__(16) short Wlds[2048 * 8];

    const int t = threadIdx.x;
    const int lane = t & 63;
    const int w = t >> 6;
    const int g = lane >> 4;

    {
        const uint4* Wg = reinterpret_cast<const uint4*>(Wb);
        uint4* L = reinterpret_cast<uint4*>(Wlds);
#pragma unroll
        for (int i = 0; i < 8; ++i) {
            int c = t + i * 256;
            int l = c & 63;
            int ks = (c >> 6) & 3;
            int tl = c >> 8;
            int row = 16 * tl + (l & 15);
            L[c] = Wg[row * 16 + ks * 4 + (l >> 4)];
        }
    }
    __syncthreads();

    short8 A[8][4];
    {
        const short8* L8 = reinterpret_cast<const short8*>(Wlds);
#pragma unroll
        for (int t8 = 0; t8 < 8; ++t8)
#pragma unroll
            for (int ks = 0; ks < 4; ++ks)
                A[t8][ks] = L8[(t8 * 4 + ks) * 64 + lane];
    }

    const int wgid = blockIdx.x * 4 + w;
    char* yb = reinterpret_cast<char*>(y);

    for (int tile = wgid; tile < NTILES; tile += GEMM_WAVES) {
        const int v0 = tile * 16;
        const int row = v0 + (lane & 15);
        const float4* xr = reinterpret_cast<const float4*>(x + (size_t)row * CD);

        float4 xf[8];
#pragma unroll
        for (int ks = 0; ks < 4; ++ks) {
            xf[2 * ks]     = xr[8 * ks + 2 * g];
            xf[2 * ks + 1] = xr[8 * ks + 2 * g + 1];
        }

        f32x4 acc[8];
#pragma unroll
        for (int t8 = 0; t8 < 8; ++t8) acc[t8] = (f32x4){0.f, 0.f, 0.f, 0.f};

#pragma unroll
        for (int ks = 0; ks < 4; ++ks) {
            short8 B;
            const float* f = reinterpret_cast<const float*>(&xf[2 * ks]);
#pragma unroll
            for (int j = 0; j < 8; ++j) B[j] = bf16of(f[j]);
#pragma unroll
            for (int t8 = 0; t8 < 8; ++t8)
                acc[t8] = __builtin_amdgcn_mfma_f32_16x16x32_bf16(A[t8][ks], B, acc[t8], 0, 0, 0);
        }

        const size_t rb = (size_t)(v0 + (lane & 15)) * 256;
#pragma unroll
        for (int t8 = 0; t8 < 8; ++t8) {
            ushort4 o;
            o.x = (unsigned short)bf16of(acc[t8][0]);
            o.y = (unsigned short)bf16of(acc[t8][1]);
            o.z = (unsigned short)bf16of(acc[t8][2]);
            o.w = (unsigned short)bf16of(acc[t8][3]);
            *reinterpret_cast<ushort4*>(yb + rb + t8 * 32 + g * 8) = o;
        }
    }
}

// ---------------- pc: per-chunk bucket histogram ----------------
__global__ __launch_bounds__(1024) void pc(const int* __restrict__ rows,
                                           int* __restrict__ cnt) {
    __shared__ int hist[NBUCK];
    const int t = threadIdx.x;
    for (int i = t; i < NBUCK; i += 1024) hist[i] = 0;
    __syncthreads();
    const int e0 = blockIdx.x * CHUNK;
    const int e1 = min(NE, e0 + CHUNK);
    for (int e = e0 + t; e < e1; e += 1024)
        atomicAdd(&hist[rows[e] >> 6], 1);
    __syncthreads();
    for (int i = t; i < NBUCK; i += 1024)
        cnt[(size_t)blockIdx.x * NBUCK + i] = hist[i];
}

// ---------------- ps: cross-block exclusive prefix per bucket (in-place) ----------------
__global__ __launch_bounds__(256) void ps(int* __restrict__ cnt,
                                          int* __restrict__ tot) {
    int g = blockIdx.x * 256 + threadIdx.x;
    if (g >= NBUCK) return;
    int running = 0;
    for (int blk = 0; blk < NBLK; ++blk) {
        int idx = blk * NBUCK + g;
        int c = cnt[idx];
        cnt[idx] = running;       // rel[blk][bk]
        running += c;
    }
    tot[g] = running;
}

// ---------------- pt: scan bucket totals -> start[0..NBUCK] ----------------
__global__ __launch_bounds__(1024) void pt(const int* __restrict__ tot,
                                           int* __restrict__ start) {
    __shared__ int s[1024];
    const int t = threadIdx.x;
    if (t == 0) start[NBUCK] = NE;
    int carry = 0;
    for (int c = 0; c < 4; ++c) {
        int idx = c * 1024 + t;
        int v = (idx < NBUCK) ? tot[idx] : 0;
        s[t] = v;
        __syncthreads();
        for (int d = 1; d < 1024; d <<= 1) {
            int add = (t >= d) ? s[t - d] : 0;
            __syncthreads();
            s[t] += add;
            __syncthreads();
        }
        if (idx < NBUCK) start[idx] = carry + s[t] - v;
        carry += s[1023];
        __syncthreads();
    }
}

// ---------------- px: scatter edges into bucket order (block-owned runs) ----------------
__global__ __launch_bounds__(1024) void px(const int* __restrict__ rows,
                                           const int* __restrict__ cols,
                                           const float* __restrict__ vals,
                                           const int* __restrict__ cnt,
                                           const int* __restrict__ start,
                                           int2* __restrict__ scat) {
    __shared__ int cur[NBUCK];
    const int t = threadIdx.x;
    for (int i = t; i < NBUCK; i += 1024)
        cur[i] = start[i] + cnt[(size_t)blockIdx.x * NBUCK + i];
    __syncthreads();
    const int e0 = blockIdx.x * CHUNK;
    const int e1 = min(NE, e0 + CHUNK);
    for (int e = e0 + t; e < e1; e += 1024) {
        int r = rows[e];
        int pos = atomicAdd(&cur[r >> 6], 1);
        scat[pos] = make_int2(cols[e] | ((r & 63) << 18), __float_as_int(vals[e]));
    }
}

// ---------------- k_sort: within-bucket counting sort by local row ----------------
// One block per bucket. Emits row-sorted scat2 + per-row CSR offsets.
__global__ __launch_bounds__(256) void k_sort(const int* __restrict__ start,
                                              const int2* __restrict__ scat,
                                              int2* __restrict__ scat2,
                                              int* __restrict__ rowoff) {
    __shared__ int rcnt[64], rinc[64], cur[64];
    const int t = threadIdx.x;
    const int b = blockIdx.x;
    const int s0 = start[b], s1 = start[b + 1];

    if (t < 64) rcnt[t] = 0;
    __syncthreads();
    for (int e = s0 + t; e < s1; e += 256)
        atomicAdd(&rcnt[(scat[e].x >> 18) & 63], 1);
    __syncthreads();
    if (t < 64) rinc[t] = rcnt[t];
    __syncthreads();
    for (int d = 1; d < 64; d <<= 1) {
        int add = 0;
        if (t < 64 && t >= d) add = rinc[t - d];
        __syncthreads();
        if (t < 64) rinc[t] += add;
        __syncthreads();
    }
    if (t < 64) {
        int excl = rinc[t] - rcnt[t];
        cur[t] = excl;
        rowoff[b * 64 + t] = s0 + excl;
    }
    if (b == NBUCK - 1 && t == 0) rowoff[NV] = NE;
    __syncthreads();
    for (int e = s0 + t; e < s1; e += 256) {
        int2 p = scat[e];            // L2-hot re-read
        int lr = (p.x >> 18) & 63;
        int pos = s0 + atomicAdd(&cur[lr], 1);
        scat2[pos] = p;
    }
}

// ---------------- gather: 1 wave per row, reg acc, bf16 y, unroll 4 (proven r5) ----------------
__global__ __launch_bounds__(256) void k_gather(const int* __restrict__ rowoff,
                                                const int2* __restrict__ scat2,
                                                const unsigned* __restrict__ y,
                                                const float* __restrict__ b,
                                                float* __restrict__ out) {
    const int wid = threadIdx.x >> 6;
    const int lane = threadIdx.x & 63;
    const int row = blockIdx.x * 4 + wid;

    float2 acc = reinterpret_cast<const float2*>(b)[lane];   // channels 2l, 2l+1

    int e = rowoff[row];
    const int end = rowoff[row + 1];

    for (; e + 4 <= end; e += 4) {
        int2 p0 = scat2[e + 0];
        int2 p1 = scat2[e + 1];
        int2 p2 = scat2[e + 2];
        int2 p3 = scat2[e + 3];
        unsigned u0 = y[(size_t)(p0.x & 0x3ffff) * 64 + lane];
        unsigned u1 = y[(size_t)(p1.x & 0x3ffff) * 64 + lane];
        unsigned u2 = y[(size_t)(p2.x & 0x3ffff) * 64 + lane];
        unsigned u3 = y[(size_t)(p3.x & 0x3ffff) * 64 + lane];
        float v0 = __int_as_float(p0.y), v1 = __int_as_float(p1.y);
        float v2 = __int_as_float(p2.y), v3 = __int_as_float(p3.y);
        acc.x += v0 * __uint_as_float(u0 << 16) + v1 * __uint_as_float(u1 << 16) +
                 v2 * __uint_as_float(u2 << 16) + v3 * __uint_as_float(u3 << 16);
        acc.y += v0 * __uint_as_float(u0 & 0xffff0000u) + v1 * __uint_as_float(u1 & 0xffff0000u) +
                 v2 * __uint_as_float(u2 & 0xffff0000u) + v3 * __uint_as_float(u3 & 0xffff0000u);
    }
    for (; e < end; ++e) {
        int2 p = scat2[e];
        unsigned u = y[(size_t)(p.x & 0x3ffff) * 64 + lane];
        float v = __int_as_float(p.y);
        acc.x += v * __uint_as_float(u << 16);
        acc.y += v * __uint_as_float(u & 0xffff0000u);
    }
    reinterpret_cast<float2*>(out)[(size_t)row * 64 + lane] = acc;
}

extern "C" void kernel_launch(void* const* d_in, const int* in_sizes, int n_in,
                              void* d_out, int out_size, void* d_ws, size_t ws_size,
                              hipStream_t stream) {
    const float* x    = (const float*)d_in[0];
    const int*   rows = (const int*)d_in[1];
    const int*   cols = (const int*)d_in[2];
    const float* vals = (const float*)d_in[3];
    const float* Wm   = (const float*)d_in[4];
    const float* b    = (const float*)d_in[5];
    float* out = (float*)d_out;

    char* ws = (char*)d_ws;
    unsigned short* y  = (unsigned short*)(ws + Y_OFF);
    unsigned short* Wb = (unsigned short*)(ws + WB_OFF);
    int* cnt           = (int*)(ws + CNT_OFF);
    int* tot           = (int*)(ws + TOT_OFF);
    int* start         = (int*)(ws + START_OFF);
    int2* scat         = (int2*)(ws + SCAT_OFF);
    int* rowoff        = (int*)(ws + ROWOFF_OFF);
    int2* scat2        = (int2*)(ws + SCAT2_OFF);

    k_cvtW<<<16, 256, 0, stream>>>(Wm, Wb);
    gemm_mfma<<<GEMM_BLOCKS, 256, 0, stream>>>(x, Wb, y);
    pc<<<NBLK, 1024, 0, stream>>>(rows, cnt);
    ps<<<(NBUCK + 255) / 256, 256, 0, stream>>>(cnt, tot);
    pt<<<1, 1024, 0, stream>>>(tot, start);
    px<<<NBLK, 1024, 0, stream>>>(rows, cols, vals, cnt, start, scat);
    k_sort<<<NBUCK, 256, 0, stream>>>(start, scat, scat2, rowoff);
    k_gather<<<NV / 4, 256, 0, stream>>>(rowoff, scat2, (const unsigned*)y, b, out);
}

// Round 8
// 193.720 us; speedup vs baseline: 6.3513x; 1.2716x over previous
//
#include <hip/hip_runtime.h>

#define NV 200000
#define NE 1600000
#define CD 128
#define NBUCK 3125            // NV/64 buckets of 64 rows
#define NBLK 64
#define CHUNK 25600           // NBLK*CHUNK = 1,638,400 >= NE; run ~8 int2 = 1 line

// ---- workspace layout (bytes) ----
#define Y_OFF      0UL           // y bf16-packed: NV*CD*2 = 51,200,000
#define WB_OFF     51200000UL    // W bf16: 32,768
#define CNT_OFF    51232768UL    // NBLK*NBUCK ints = 800,000
#define TOT_OFF    52032768UL    // NBUCK ints
#define START_OFF  52045312UL    // NBUCK+1 ints
#define SCAT_OFF   52058112UL    // NE int2 = 12,800,000
#define ROWOFF_OFF 64858112UL    // NV+1 ints
#define SCAT2_OFF  65658368UL    // NE int2 = 12,800,000 (end ~78.5 MB)

typedef short  short8 __attribute__((ext_vector_type(8)));
typedef float  f32x4  __attribute__((ext_vector_type(4)));

__device__ __forceinline__ short bf16of(float f) {
    __bf16 h = (__bf16)f;
    return __builtin_bit_cast(short, h);
}

// ---------------- Kernel 0: W fp32 -> bf16 ----------------
__global__ __launch_bounds__(256) void k_cvtW(const float* __restrict__ W,
                                              unsigned short* __restrict__ Wb) {
    int i = blockIdx.x * 256 + threadIdx.x;
    float4 wv = reinterpret_cast<const float4*>(W)[i];
    ushort4 o;
    o.x = (unsigned short)bf16of(wv.x);
    o.y = (unsigned short)bf16of(wv.y);
    o.z = (unsigned short)bf16of(wv.z);
    o.w = (unsigned short)bf16of(wv.w);
    reinterpret_cast<ushort4*>(Wb)[i] = o;
}

// ---------------- Kernel 1: y(bf16) = x @ W^T via MFMA (proven round 5) ----------------
#define GEMM_BLOCKS 512
#define GEMM_WAVES (GEMM_BLOCKS * 4)
#define NTILES (NV / 16)

__global__ __launch_bounds__(256, 2) void gemm_mfma(const float* __restrict__ x,
                                                    const unsigned short* __restrict__ Wb,
                                                    unsigned short* __restrict__ y) {
    __shared__ __align__(16) short Wlds[2048 * 8];

    const int t = threadIdx.x;
    const int lane = t & 63;
    const int w = t >> 6;
    const int g = lane >> 4;

    {
        const uint4* Wg = reinterpret_cast<const uint4*>(Wb);
        uint4* L = reinterpret_cast<uint4*>(Wlds);
#pragma unroll
        for (int i = 0; i < 8; ++i) {
            int c = t + i * 256;
            int l = c & 63;
            int ks = (c >> 6) & 3;
            int tl = c >> 8;
            int row = 16 * tl + (l & 15);
            L[c] = Wg[row * 16 + ks * 4 + (l >> 4)];
        }
    }
    __syncthreads();

    short8 A[8][4];
    {
        const short8* L8 = reinterpret_cast<const short8*>(Wlds);
#pragma unroll
        for (int t8 = 0; t8 < 8; ++t8)
#pragma unroll
            for (int ks = 0; ks < 4; ++ks)
                A[t8][ks] = L8[(t8 * 4 + ks) * 64 + lane];
    }

    const int wgid = blockIdx.x * 4 + w;
    char* yb = reinterpret_cast<char*>(y);

    for (int tile = wgid; tile < NTILES; tile += GEMM_WAVES) {
        const int v0 = tile * 16;
        const int row = v0 + (lane & 15);
        const float4* xr = reinterpret_cast<const float4*>(x + (size_t)row * CD);

        float4 xf[8];
#pragma unroll
        for (int ks = 0; ks < 4; ++ks) {
            xf[2 * ks]     = xr[8 * ks + 2 * g];
            xf[2 * ks + 1] = xr[8 * ks + 2 * g + 1];
        }

        f32x4 acc[8];
#pragma unroll
        for (int t8 = 0; t8 < 8; ++t8) acc[t8] = (f32x4){0.f, 0.f, 0.f, 0.f};

#pragma unroll
        for (int ks = 0; ks < 4; ++ks) {
            short8 B;
            const float* f = reinterpret_cast<const float*>(&xf[2 * ks]);
#pragma unroll
            for (int j = 0; j < 8; ++j) B[j] = bf16of(f[j]);
#pragma unroll
            for (int t8 = 0; t8 < 8; ++t8)
                acc[t8] = __builtin_amdgcn_mfma_f32_16x16x32_bf16(A[t8][ks], B, acc[t8], 0, 0, 0);
        }

        const size_t rb = (size_t)(v0 + (lane & 15)) * 256;
#pragma unroll
        for (int t8 = 0; t8 < 8; ++t8) {
            ushort4 o;
            o.x = (unsigned short)bf16of(acc[t8][0]);
            o.y = (unsigned short)bf16of(acc[t8][1]);
            o.z = (unsigned short)bf16of(acc[t8][2]);
            o.w = (unsigned short)bf16of(acc[t8][3]);
            *reinterpret_cast<ushort4*>(yb + rb + t8 * 32 + g * 8) = o;
        }
    }
}

// ---------------- pc: per-chunk bucket histogram ----------------
__global__ __launch_bounds__(1024) void pc(const int* __restrict__ rows,
                                           int* __restrict__ cnt) {
    __shared__ int hist[NBUCK];
    const int t = threadIdx.x;
    for (int i = t; i < NBUCK; i += 1024) hist[i] = 0;
    __syncthreads();
    const int e0 = blockIdx.x * CHUNK;
    const int e1 = min(NE, e0 + CHUNK);
    for (int e = e0 + t; e < e1; e += 1024)
        atomicAdd(&hist[rows[e] >> 6], 1);
    __syncthreads();
    for (int i = t; i < NBUCK; i += 1024)
        cnt[(size_t)blockIdx.x * NBUCK + i] = hist[i];
}

// ---------------- ps: cross-block exclusive prefix per bucket (in-place) ----------------
__global__ __launch_bounds__(256) void ps(int* __restrict__ cnt,
                                          int* __restrict__ tot) {
    int g = blockIdx.x * 256 + threadIdx.x;
    if (g >= NBUCK) return;
    int running = 0;
    for (int blk = 0; blk < NBLK; ++blk) {
        int idx = blk * NBUCK + g;
        int c = cnt[idx];
        cnt[idx] = running;       // rel[blk][bk]
        running += c;
    }
    tot[g] = running;
}

// ---------------- pt: scan bucket totals -> start[0..NBUCK] ----------------
__global__ __launch_bounds__(1024) void pt(const int* __restrict__ tot,
                                           int* __restrict__ start) {
    __shared__ int s[1024];
    const int t = threadIdx.x;
    if (t == 0) start[NBUCK] = NE;
    int carry = 0;
    for (int c = 0; c < 4; ++c) {
        int idx = c * 1024 + t;
        int v = (idx < NBUCK) ? tot[idx] : 0;
        s[t] = v;
        __syncthreads();
        for (int d = 1; d < 1024; d <<= 1) {
            int add = (t >= d) ? s[t - d] : 0;
            __syncthreads();
            s[t] += add;
            __syncthreads();
        }
        if (idx < NBUCK) start[idx] = carry + s[t] - v;
        carry += s[1023];
        __syncthreads();
    }
}

// ---------------- px: scatter edges into bucket order (block-owned runs) ----------------
__global__ __launch_bounds__(1024) void px(const int* __restrict__ rows,
                                           const int* __restrict__ cols,
                                           const float* __restrict__ vals,
                                           const int* __restrict__ cnt,
                                           const int* __restrict__ start,
                                           int2* __restrict__ scat) {
    __shared__ int cur[NBUCK];
    const int t = threadIdx.x;
    for (int i = t; i < NBUCK; i += 1024)
        cur[i] = start[i] + cnt[(size_t)blockIdx.x * NBUCK + i];
    __syncthreads();
    const int e0 = blockIdx.x * CHUNK;
    const int e1 = min(NE, e0 + CHUNK);
    for (int e = e0 + t; e < e1; e += 1024) {
        int r = rows[e];
        int pos = atomicAdd(&cur[r >> 6], 1);
        scat[pos] = make_int2(cols[e] | ((r & 63) << 18), __float_as_int(vals[e]));
    }
}

// ---------------- k_sort: within-bucket counting sort by local row ----------------
__global__ __launch_bounds__(256) void k_sort(const int* __restrict__ start,
                                              const int2* __restrict__ scat,
                                              int2* __restrict__ scat2,
                                              int* __restrict__ rowoff) {
    __shared__ int rcnt[64], rinc[64], cur[64];
    const int t = threadIdx.x;
    const int b = blockIdx.x;
    const int s0 = start[b], s1 = start[b + 1];

    if (t < 64) rcnt[t] = 0;
    __syncthreads();
    for (int e = s0 + t; e < s1; e += 256)
        atomicAdd(&rcnt[(scat[e].x >> 18) & 63], 1);
    __syncthreads();
    if (t < 64) rinc[t] = rcnt[t];
    __syncthreads();
    for (int d = 1; d < 64; d <<= 1) {
        int add = 0;
        if (t < 64 && t >= d) add = rinc[t - d];
        __syncthreads();
        if (t < 64) rinc[t] += add;
        __syncthreads();
    }
    if (t < 64) {
        int excl = rinc[t] - rcnt[t];
        cur[t] = excl;
        rowoff[b * 64 + t] = s0 + excl;
    }
    if (b == NBUCK - 1 && t == 0) rowoff[NV] = NE;
    __syncthreads();
    for (int e = s0 + t; e < s1; e += 256) {
        int2 p = scat[e];            // L1/L2-hot re-read
        int lr = (p.x >> 18) & 63;
        int pos = s0 + atomicAdd(&cur[lr], 1);
        scat2[pos] = p;
    }
}

// ---------------- gather: 1 wave per row, split-half edges, NT out store ----------------
// Lanes 0-31 process even edges, 32-63 odd edges of the same row; each lane holds
// 4 channels (uint2 of packed bf16 per y-load -> one VMEM covers 2 edges/512 B).
#define BFLO(u) __uint_as_float((u) << 16)
#define BFHI(u) __uint_as_float((u) & 0xffff0000u)

__global__ __launch_bounds__(256) void k_gather(const int* __restrict__ rowoff,
                                                const int2* __restrict__ scat2,
                                                const unsigned* __restrict__ y,
                                                const float* __restrict__ b,
                                                float* __restrict__ out) {
    const int wid = threadIdx.x >> 6;
    const int lane = threadIdx.x & 63;
    const int half = lane >> 5;
    const int sl = lane & 31;
    const int row = blockIdx.x * 4 + wid;

    const int s0 = rowoff[row];
    const int n = rowoff[row + 1] - s0;
    const int nh = (n - half + 1) >> 1;   // edges handled by this half

    float4 acc = half ? make_float4(0.f, 0.f, 0.f, 0.f)
                      : reinterpret_cast<const float4*>(b)[sl];   // chans 4sl..4sl+3
    const uint2* y2 = reinterpret_cast<const uint2*>(y);

    int k = 0;
    int e = s0 + half;
    for (; k + 4 <= nh; k += 4, e += 8) {
        int2 p0 = scat2[e];
        int2 p1 = scat2[e + 2];
        int2 p2 = scat2[e + 4];
        int2 p3 = scat2[e + 6];
        uint2 u0 = y2[(size_t)(p0.x & 0x3ffff) * 32 + sl];
        uint2 u1 = y2[(size_t)(p1.x & 0x3ffff) * 32 + sl];
        uint2 u2 = y2[(size_t)(p2.x & 0x3ffff) * 32 + sl];
        uint2 u3 = y2[(size_t)(p3.x & 0x3ffff) * 32 + sl];
        float v0 = __int_as_float(p0.y), v1 = __int_as_float(p1.y);
        float v2 = __int_as_float(p2.y), v3 = __int_as_float(p3.y);
        acc.x += (v0 * BFLO(u0.x) + v1 * BFLO(u1.x)) + (v2 * BFLO(u2.x) + v3 * BFLO(u3.x));
        acc.y += (v0 * BFHI(u0.x) + v1 * BFHI(u1.x)) + (v2 * BFHI(u2.x) + v3 * BFHI(u3.x));
        acc.z += (v0 * BFLO(u0.y) + v1 * BFLO(u1.y)) + (v2 * BFLO(u2.y) + v3 * BFLO(u3.y));
        acc.w += (v0 * BFHI(u0.y) + v1 * BFHI(u1.y)) + (v2 * BFHI(u2.y) + v3 * BFHI(u3.y));
    }
    for (; k < nh; ++k, e += 2) {
        int2 p = scat2[e];
        uint2 u = y2[(size_t)(p.x & 0x3ffff) * 32 + sl];
        float v = __int_as_float(p.y);
        acc.x += v * BFLO(u.x);
        acc.y += v * BFHI(u.x);
        acc.z += v * BFLO(u.y);
        acc.w += v * BFHI(u.y);
    }

    // combine halves
    acc.x += __shfl_xor(acc.x, 32);
    acc.y += __shfl_xor(acc.y, 32);
    acc.z += __shfl_xor(acc.z, 32);
    acc.w += __shfl_xor(acc.w, 32);

    if (half == 0) {
        f32x4 st = {acc.x, acc.y, acc.z, acc.w};
        __builtin_nontemporal_store(st, (f32x4*)(out + (size_t)row * CD + sl * 4));
    }
}

extern "C" void kernel_launch(void* const* d_in, const int* in_sizes, int n_in,
                              void* d_out, int out_size, void* d_ws, size_t ws_size,
                              hipStream_t stream) {
    const float* x    = (const float*)d_in[0];
    const int*   rows = (const int*)d_in[1];
    const int*   cols = (const int*)d_in[2];
    const float* vals = (const float*)d_in[3];
    const float* Wm   = (const float*)d_in[4];
    const float* b    = (const float*)d_in[5];
    float* out = (float*)d_out;

    char* ws = (char*)d_ws;
    unsigned short* y  = (unsigned short*)(ws + Y_OFF);
    unsigned short* Wb = (unsigned short*)(ws + WB_OFF);
    int* cnt           = (int*)(ws + CNT_OFF);
    int* tot           = (int*)(ws + TOT_OFF);
    int* start         = (int*)(ws + START_OFF);
    int2* scat         = (int2*)(ws + SCAT_OFF);
    int* rowoff        = (int*)(ws + ROWOFF_OFF);
    int2* scat2        = (int2*)(ws + SCAT2_OFF);

    k_cvtW<<<16, 256, 0, stream>>>(Wm, Wb);
    gemm_mfma<<<GEMM_BLOCKS, 256, 0, stream>>>(x, Wb, y);
    pc<<<NBLK, 1024, 0, stream>>>(rows, cnt);
    ps<<<(NBUCK + 255) / 256, 256, 0, stream>>>(cnt, tot);
    pt<<<1, 1024, 0, stream>>>(tot, start);
    px<<<NBLK, 1024, 0, stream>>>(rows, cols, vals, cnt, start, scat);
    k_sort<<<NBUCK, 256, 0, stream>>>(start, scat, scat2, rowoff);
    k_gather<<<NV / 4, 256, 0, stream>>>(rowoff, scat2, (const unsigned*)y, b, out);
}

// Round 9
// 184.126 us; speedup vs baseline: 6.6823x; 1.0521x over previous
//
#include <hip/hip_runtime.h>

#define NV 200000
#define NE 1600000
#define CD 128
#define NBUCK 3125            // NV/64 buckets of 64 rows
#define NBLK 64
#define CHUNK 25600           // NBLK*CHUNK = 1,638,400 >= NE

// ---- workspace layout (bytes) ----
#define Y_OFF      0UL           // y bf16-packed: NV*CD*2 = 51,200,000
#define CNT_OFF    51232768UL    // NBLK*NBUCK ints = 800,000
#define TOT_OFF    52032768UL    // NBUCK ints
#define START_OFF  52045312UL    // NBUCK+1 ints
#define SCAT_OFF   52058112UL    // NE int2 = 12,800,000
#define ROWOFF_OFF 64858112UL    // NV+1 ints
#define SCAT2_OFF  65658368UL    // NE int2 = 12,800,000 (end ~78.5 MB)

typedef short  short8 __attribute__((ext_vector_type(8)));
typedef float  f32x4  __attribute__((ext_vector_type(4)));

__device__ __forceinline__ unsigned bf16pair(float a, float b) {
    unsigned ua = __float_as_uint(a);
    unsigned ub = __float_as_uint(b);
    ua += 0x7fffu + ((ua >> 16) & 1u);   // RNE
    ub += 0x7fffu + ((ub >> 16) & 1u);
    return (ua >> 16) | (ub & 0xffff0000u);
}

__device__ __forceinline__ short bf16of(float f) {
    __bf16 h = (__bf16)f;
    return __builtin_bit_cast(short, h);
}

// ---------------- Fused Kernel 1: [pc histogram | gemm y=x@W^T via MFMA] ----------------
// Blocks 0..63: pc (per-chunk bucket histogram of rows) — scheduled first, overlaps gemm.
// Blocks 64..575: gemm, converting fp32 W -> bf16 inline while staging LDS.
#define PC_BLOCKS 64
#define GEMM_BLOCKS 512
#define GEMM_WAVES (GEMM_BLOCKS * 4)
#define NTILES (NV / 16)

__global__ __launch_bounds__(256, 2) void gemm_pc(const float* __restrict__ x,
                                                  const float* __restrict__ Wm,
                                                  unsigned short* __restrict__ y,
                                                  const int* __restrict__ rows,
                                                  int* __restrict__ cnt) {
    __shared__ __align__(16) char smem[32768];
    const int t = threadIdx.x;

    if (blockIdx.x < PC_BLOCKS) {
        // ---- pc body (256 threads) ----
        int* hist = reinterpret_cast<int*>(smem);
        const int blk = blockIdx.x;
        for (int i = t; i < NBUCK; i += 256) hist[i] = 0;
        __syncthreads();
        const int e0 = blk * CHUNK;
        const int e1 = min(NE, e0 + CHUNK);
        for (int e = e0 + t; e < e1; e += 256)
            atomicAdd(&hist[rows[e] >> 6], 1);
        __syncthreads();
        for (int i = t; i < NBUCK; i += 256)
            cnt[(size_t)blk * NBUCK + i] = hist[i];
        return;
    }

    // ---- gemm body ----
    short* Wlds = reinterpret_cast<short*>(smem);
    const int lane = t & 63;
    const int w = t >> 6;
    const int g = lane >> 4;

    // stage W fragments into LDS, converting fp32->bf16 on the fly
    {
        const float4* Wf4 = reinterpret_cast<const float4*>(Wm);   // 32 float4 per row
        uint4* L = reinterpret_cast<uint4*>(Wlds);
#pragma unroll
        for (int i = 0; i < 8; ++i) {
            int c = t + i * 256;
            int l = c & 63;
            int ks = (c >> 6) & 3;
            int tl = c >> 8;
            int row = 16 * tl + (l & 15);
            int j = ks * 4 + (l >> 4);       // uint4 index within row (8 bf16)
            float4 wa = Wf4[row * 32 + j * 2];
            float4 wb = Wf4[row * 32 + j * 2 + 1];
            uint4 u;
            u.x = bf16pair(wa.x, wa.y);
            u.y = bf16pair(wa.z, wa.w);
            u.z = bf16pair(wb.x, wb.y);
            u.w = bf16pair(wb.z, wb.w);
            L[c] = u;
        }
    }
    __syncthreads();

    short8 A[8][4];
    {
        const short8* L8 = reinterpret_cast<const short8*>(Wlds);
#pragma unroll
        for (int t8 = 0; t8 < 8; ++t8)
#pragma unroll
            for (int ks = 0; ks < 4; ++ks)
                A[t8][ks] = L8[(t8 * 4 + ks) * 64 + lane];
    }

    const int wgid = (blockIdx.x - PC_BLOCKS) * 4 + w;
    char* yb = reinterpret_cast<char*>(y);

    for (int tile = wgid; tile < NTILES; tile += GEMM_WAVES) {
        const int v0 = tile * 16;
        const int row = v0 + (lane & 15);
        const float4* xr = reinterpret_cast<const float4*>(x + (size_t)row * CD);

        float4 xf[8];
#pragma unroll
        for (int ks = 0; ks < 4; ++ks) {
            xf[2 * ks]     = xr[8 * ks + 2 * g];
            xf[2 * ks + 1] = xr[8 * ks + 2 * g + 1];
        }

        f32x4 acc[8];
#pragma unroll
        for (int t8 = 0; t8 < 8; ++t8) acc[t8] = (f32x4){0.f, 0.f, 0.f, 0.f};

#pragma unroll
        for (int ks = 0; ks < 4; ++ks) {
            short8 B;
            const float* f = reinterpret_cast<const float*>(&xf[2 * ks]);
#pragma unroll
            for (int j = 0; j < 8; ++j) B[j] = bf16of(f[j]);
#pragma unroll
            for (int t8 = 0; t8 < 8; ++t8)
                acc[t8] = __builtin_amdgcn_mfma_f32_16x16x32_bf16(A[t8][ks], B, acc[t8], 0, 0, 0);
        }

        const size_t rb = (size_t)(v0 + (lane & 15)) * 256;
#pragma unroll
        for (int t8 = 0; t8 < 8; ++t8) {
            ushort4 o;
            o.x = (unsigned short)bf16of(acc[t8][0]);
            o.y = (unsigned short)bf16of(acc[t8][1]);
            o.z = (unsigned short)bf16of(acc[t8][2]);
            o.w = (unsigned short)bf16of(acc[t8][3]);
            *reinterpret_cast<ushort4*>(yb + rb + t8 * 32 + g * 8) = o;
        }
    }
}

// ---------------- ps: cross-block exclusive prefix per bucket (in-place) ----------------
__global__ __launch_bounds__(256) void ps(int* __restrict__ cnt,
                                          int* __restrict__ tot) {
    int g = blockIdx.x * 256 + threadIdx.x;
    if (g >= NBUCK) return;
    int running = 0;
    for (int blk = 0; blk < NBLK; ++blk) {
        int idx = blk * NBUCK + g;
        int c = cnt[idx];
        cnt[idx] = running;       // rel[blk][bk]
        running += c;
    }
    tot[g] = running;
}

// ---------------- pt: scan bucket totals -> start[0..NBUCK] ----------------
__global__ __launch_bounds__(1024) void pt(const int* __restrict__ tot,
                                           int* __restrict__ start) {
    __shared__ int s[1024];
    const int t = threadIdx.x;
    if (t == 0) start[NBUCK] = NE;
    int carry = 0;
    for (int c = 0; c < 4; ++c) {
        int idx = c * 1024 + t;
        int v = (idx < NBUCK) ? tot[idx] : 0;
        s[t] = v;
        __syncthreads();
        for (int d = 1; d < 1024; d <<= 1) {
            int add = (t >= d) ? s[t - d] : 0;
            __syncthreads();
            s[t] += add;
            __syncthreads();
        }
        if (idx < NBUCK) start[idx] = carry + s[t] - v;
        carry += s[1023];
        __syncthreads();
    }
}

// ---------------- px: scatter edges into bucket order (block-owned runs) ----------------
__global__ __launch_bounds__(1024) void px(const int* __restrict__ rows,
                                           const int* __restrict__ cols,
                                           const float* __restrict__ vals,
                                           const int* __restrict__ cnt,
                                           const int* __restrict__ start,
                                           int2* __restrict__ scat) {
    __shared__ int cur[NBUCK];
    const int t = threadIdx.x;
    for (int i = t; i < NBUCK; i += 1024)
        cur[i] = start[i] + cnt[(size_t)blockIdx.x * NBUCK + i];
    __syncthreads();
    const int e0 = blockIdx.x * CHUNK;
    const int e1 = min(NE, e0 + CHUNK);
    for (int e = e0 + t; e < e1; e += 1024) {
        int r = rows[e];
        int pos = atomicAdd(&cur[r >> 6], 1);
        scat[pos] = make_int2(cols[e] | ((r & 63) << 18), __float_as_int(vals[e]));
    }
}

// ---------------- k_sort: within-bucket counting sort by local row ----------------
__global__ __launch_bounds__(256) void k_sort(const int* __restrict__ start,
                                              const int2* __restrict__ scat,
                                              int2* __restrict__ scat2,
                                              int* __restrict__ rowoff) {
    __shared__ int rcnt[64], rinc[64], cur[64];
    const int t = threadIdx.x;
    const int b = blockIdx.x;
    const int s0 = start[b], s1 = start[b + 1];

    if (t < 64) rcnt[t] = 0;
    __syncthreads();
    for (int e = s0 + t; e < s1; e += 256)
        atomicAdd(&rcnt[(scat[e].x >> 18) & 63], 1);
    __syncthreads();
    if (t < 64) rinc[t] = rcnt[t];
    __syncthreads();
    for (int d = 1; d < 64; d <<= 1) {
        int add = 0;
        if (t < 64 && t >= d) add = rinc[t - d];
        __syncthreads();
        if (t < 64) rinc[t] += add;
        __syncthreads();
    }
    if (t < 64) {
        int excl = rinc[t] - rcnt[t];
        cur[t] = excl;
        rowoff[b * 64 + t] = s0 + excl;
    }
    if (b == NBUCK - 1 && t == 0) rowoff[NV] = NE;
    __syncthreads();
    for (int e = s0 + t; e < s1; e += 256) {
        int2 p = scat[e];            // L1/L2-hot re-read
        int lr = (p.x >> 18) & 63;
        int pos = s0 + atomicAdd(&cur[lr], 1);
        scat2[pos] = p;
    }
}

// ---------------- gather: 1 wave per row, quarter-split (16 lanes/edge, uint4) ----------------
// One y-load instruction covers 4 edges (64 lanes x 16 B = 4 x 256 B rows).
#define BFLO(u) __uint_as_float((u) << 16)
#define BFHI(u) __uint_as_float((u) & 0xffff0000u)

__global__ __launch_bounds__(256) void k_gather(const int* __restrict__ rowoff,
                                                const int2* __restrict__ scat2,
                                                const uint4* __restrict__ y4,
                                                const float* __restrict__ b,
                                                float* __restrict__ out) {
    const int wid = threadIdx.x >> 6;
    const int lane = threadIdx.x & 63;
    const int q = lane >> 4;      // quarter: edge parity mod 4
    const int sl = lane & 15;     // chan group: chans 8*sl .. 8*sl+7
    const int row = blockIdx.x * 4 + wid;

    const int s0 = rowoff[row];
    const int n = rowoff[row + 1] - s0;

    float4 accA, accB;
    if (q == 0) {
        accA = reinterpret_cast<const float4*>(b)[2 * sl];
        accB = reinterpret_cast<const float4*>(b)[2 * sl + 1];
    } else {
        accA = make_float4(0.f, 0.f, 0.f, 0.f);
        accB = make_float4(0.f, 0.f, 0.f, 0.f);
    }

    int k = q;
    for (; k + 4 < n; k += 8) {     // 8 edges/iter across the wave, 2 per quarter
        int2 pa = scat2[s0 + k];
        int2 pb = scat2[s0 + k + 4];
        uint4 ua = y4[(size_t)(pa.x & 0x3ffff) * 16 + sl];
        uint4 ub = y4[(size_t)(pb.x & 0x3ffff) * 16 + sl];
        float va = __int_as_float(pa.y), vb = __int_as_float(pb.y);
        accA.x += va * BFLO(ua.x) + vb * BFLO(ub.x);
        accA.y += va * BFHI(ua.x) + vb * BFHI(ub.x);
        accA.z += va * BFLO(ua.y) + vb * BFLO(ub.y);
        accA.w += va * BFHI(ua.y) + vb * BFHI(ub.y);
        accB.x += va * BFLO(ua.z) + vb * BFLO(ub.z);
        accB.y += va * BFHI(ua.z) + vb * BFHI(ub.z);
        accB.z += va * BFLO(ua.w) + vb * BFLO(ub.w);
        accB.w += va * BFHI(ua.w) + vb * BFHI(ub.w);
    }
    if (k < n) {
        int2 p = scat2[s0 + k];
        uint4 u = y4[(size_t)(p.x & 0x3ffff) * 16 + sl];
        float v = __int_as_float(p.y);
        accA.x += v * BFLO(u.x);
        accA.y += v * BFHI(u.x);
        accA.z += v * BFLO(u.y);
        accA.w += v * BFHI(u.y);
        accB.x += v * BFLO(u.z);
        accB.y += v * BFHI(u.z);
        accB.z += v * BFLO(u.w);
        accB.w += v * BFHI(u.w);
    }

    // reduce across quarters (xor 16, then xor 32)
    accA.x += __shfl_xor(accA.x, 16); accA.x += __shfl_xor(accA.x, 32);
    accA.y += __shfl_xor(accA.y, 16); accA.y += __shfl_xor(accA.y, 32);
    accA.z += __shfl_xor(accA.z, 16); accA.z += __shfl_xor(accA.z, 32);
    accA.w += __shfl_xor(accA.w, 16); accA.w += __shfl_xor(accA.w, 32);
    accB.x += __shfl_xor(accB.x, 16); accB.x += __shfl_xor(accB.x, 32);
    accB.y += __shfl_xor(accB.y, 16); accB.y += __shfl_xor(accB.y, 32);
    accB.z += __shfl_xor(accB.z, 16); accB.z += __shfl_xor(accB.z, 32);
    accB.w += __shfl_xor(accB.w, 16); accB.w += __shfl_xor(accB.w, 32);

    if (q == 0) {
        f32x4 sA = {accA.x, accA.y, accA.z, accA.w};
        f32x4 sB = {accB.x, accB.y, accB.z, accB.w};
        float* o = out + (size_t)row * CD + sl * 8;
        __builtin_nontemporal_store(sA, (f32x4*)o);
        __builtin_nontemporal_store(sB, (f32x4*)(o + 4));
    }
}

extern "C" void kernel_launch(void* const* d_in, const int* in_sizes, int n_in,
                              void* d_out, int out_size, void* d_ws, size_t ws_size,
                              hipStream_t stream) {
    const float* x    = (const float*)d_in[0];
    const int*   rows = (const int*)d_in[1];
    const int*   cols = (const int*)d_in[2];
    const float* vals = (const float*)d_in[3];
    const float* Wm   = (const float*)d_in[4];
    const float* b    = (const float*)d_in[5];
    float* out = (float*)d_out;

    char* ws = (char*)d_ws;
    unsigned short* y  = (unsigned short*)(ws + Y_OFF);
    int* cnt           = (int*)(ws + CNT_OFF);
    int* tot           = (int*)(ws + TOT_OFF);
    int* start         = (int*)(ws + START_OFF);
    int2* scat         = (int2*)(ws + SCAT_OFF);
    int* rowoff        = (int*)(ws + ROWOFF_OFF);
    int2* scat2        = (int2*)(ws + SCAT2_OFF);

    gemm_pc<<<PC_BLOCKS + GEMM_BLOCKS, 256, 0, stream>>>(x, Wm, y, rows, cnt);
    ps<<<(NBUCK + 255) / 256, 256, 0, stream>>>(cnt, tot);
    pt<<<1, 1024, 0, stream>>>(tot, start);
    px<<<NBLK, 1024, 0, stream>>>(rows, cols, vals, cnt, start, scat);
    k_sort<<<NBUCK, 256, 0, stream>>>(start, scat, scat2, rowoff);
    k_gather<<<NV / 4, 256, 0, stream>>>(rowoff, scat2, (const uint4*)y, b, out);
}